// Round 8
// baseline (829.328 us; speedup 1.0000x reference)
//
#include <hip/hip_runtime.h>
#include <stdint.h>

typedef _Float16 half8 __attribute__((ext_vector_type(8)));
typedef float float4v __attribute__((ext_vector_type(4)));

// Problem constants
constexpr int kN = 100000;   // nodes
constexpr int kE = 1600000;  // edges
constexpr int kP = 500000;   // pairs
constexpr int NBS = (kN + 255) / 256;  // scan blocks = 391
constexpr int CT3 = kN / 16;           // 6250 conv wave-tiles (16 nodes, exact)
constexpr int DT3 = kP / 16;           // 31250 decoder tiles (16 pairs, exact)

// ---------------------------------------------------------------------------
// CSR build: pass1 = histogram + slot record, scan, pass2 = atomic-free fill
// ---------------------------------------------------------------------------
__global__ void deg_slot_kernel(const int* __restrict__ dst,
                                int* __restrict__ deg, int* __restrict__ slot) {
    int e = blockIdx.x * blockDim.x + threadIdx.x;
    if (e < kE) slot[e] = atomicAdd(&deg[dst[e]], 1);
}

__global__ void scan_block_sums(const int* __restrict__ deg, int* __restrict__ bsum) {
    __shared__ int red[256];
    int t = threadIdx.x;
    int i = blockIdx.x * 256 + t;
    red[t] = (i < kN) ? deg[i] : 0;
    __syncthreads();
    for (int s = 128; s > 0; s >>= 1) {
        if (t < s) red[t] += red[t + s];
        __syncthreads();
    }
    if (t == 0) bsum[blockIdx.x] = red[0];
}

__global__ void scan_bsums(const int* __restrict__ bsum, int* __restrict__ boff) {
    __shared__ int sm[512];
    int t = threadIdx.x;
    int orig = (t < NBS) ? bsum[t] : 0;
    sm[t] = orig;
    __syncthreads();
    for (int d = 1; d < 512; d <<= 1) {
        int u = (t >= d) ? sm[t - d] : 0;
        __syncthreads();
        sm[t] += u;
        __syncthreads();
    }
    if (t < NBS) boff[t] = sm[t] - orig;  // exclusive
}

__global__ void scan_write(const int* __restrict__ deg, const int* __restrict__ boff,
                           int* __restrict__ row_start) {
    __shared__ int sm[256];
    int t = threadIdx.x;
    int i = blockIdx.x * 256 + t;
    int v = (i < kN) ? deg[i] : 0;
    sm[t] = v;
    __syncthreads();
    for (int d = 1; d < 256; d <<= 1) {
        int u = (t >= d) ? sm[t - d] : 0;
        __syncthreads();
        sm[t] += u;
        __syncthreads();
    }
    int excl = sm[t] - v + boff[blockIdx.x];
    if (i < kN) row_start[i] = excl;
    if (i == kN - 1) row_start[kN] = excl + v;
}

__global__ void fill2_kernel(const int* __restrict__ src, const int* __restrict__ dst,
                             const int* __restrict__ row_start,
                             const int* __restrict__ slot, int* __restrict__ srcs) {
    int e = blockIdx.x * blockDim.x + threadIdx.x;
    if (e < kE) srcs[row_start[dst[e]] + slot[e]] = src[e];
}

// ---------------------------------------------------------------------------
// Prep: x -> fp16; weights -> fp16 hi/lo planes
// ---------------------------------------------------------------------------
__global__ void cvt_x_kernel(const float* __restrict__ x, _Float16* __restrict__ xh) {
    const int i = (blockIdx.x * 256 + threadIdx.x) * 8;
    if (i >= kN * 128) return;
    const float4 a = *(const float4*)&x[i];
    const float4 b = *(const float4*)&x[i + 4];
    half8 v;
    v[0] = (_Float16)a.x; v[1] = (_Float16)a.y; v[2] = (_Float16)a.z; v[3] = (_Float16)a.w;
    v[4] = (_Float16)b.x; v[5] = (_Float16)b.y; v[6] = (_Float16)b.z; v[7] = (_Float16)b.w;
    *(half8*)&xh[i] = v;
}

// CW1/CW2: [128 out][256 k], k<128 -> Wl, k>=128 -> Wr. M1:[128][128], M2:[64][128].
__global__ void cvt_w_kernel(
    const float* __restrict__ W1l, const float* __restrict__ W1r,
    const float* __restrict__ W2l, const float* __restrict__ W2r,
    const float* __restrict__ Wm1, const float* __restrict__ Wm2,
    _Float16* __restrict__ CW1h, _Float16* __restrict__ CW1e,
    _Float16* __restrict__ CW2h, _Float16* __restrict__ CW2e,
    _Float16* __restrict__ M1h,  _Float16* __restrict__ M2h)
{
    const int i = blockIdx.x * 256 + threadIdx.x;
    if (i < 32768) {
        const int o = i >> 8, k = i & 255;
        const float w = (k < 128) ? W1l[o * 128 + k] : W1r[o * 128 + k - 128];
        const _Float16 h = (_Float16)w;
        CW1h[i] = h; CW1e[i] = (_Float16)(w - (float)h);
    } else if (i < 65536) {
        const int j = i - 32768;
        const int o = j >> 8, k = j & 255;
        const float w = (k < 128) ? W2l[o * 128 + k] : W2r[o * 128 + k - 128];
        const _Float16 h = (_Float16)w;
        CW2h[j] = h; CW2e[j] = (_Float16)(w - (float)h);
    } else if (i < 81920) {
        const int j = i - 65536;
        M1h[j] = (_Float16)Wm1[j];
    } else if (i < 90112) {
        const int j = i - 81920;
        M2h[j] = (_Float16)Wm2[j];
    }
}

// ---------------------------------------------------------------------------
// Wave-autonomous fused SAGEConv, 16 nodes/wave, no __syncthreads.
// Gather: dynamic two-pointer ping-pong pipeline over (node, 8-row epoch)
// pairs -- two epochs always in flight per 16-lane group. First-16 neighbor
// idx prefetched per node. Control flow is group-uniform; shfl stays in-group.
// MFMA: M=16, K=256 [mean|root], weights hi+lo from L2.
// LDS: 4 waves x [16][136] fp16 = 17408 B/block.
// ---------------------------------------------------------------------------
template <bool RELU>
__global__ __launch_bounds__(256, 4) void conv_mfma(
    const _Float16* __restrict__ xin,
    const int* __restrict__ row_start,
    const int* __restrict__ srcs,
    const _Float16* __restrict__ Wh,  // [128][256]
    const _Float16* __restrict__ We,  // [128][256]
    const float* __restrict__ bias,
    _Float16* __restrict__ out)
{
    __shared__ __align__(16) _Float16 stg_all[4 * 16 * 136];
    const int wInB = threadIdx.x >> 6;
    _Float16* stg  = &stg_all[wInB * (16 * 136)];
    const int l = threadIdx.x & 63;
    const int p = l & 15;
    const int q = l >> 4;
    const int tile = blockIdx.x * 4 + wInB;
    if (tile >= CT3) return;
    const int c = p * 8;
    const int lbase = l & 48;

    // Group's 4 nodes: n_s = tile*16 + s*4 + q
    int j0[4], j1[4];
#pragma unroll
    for (int s = 0; s < 4; s++) {
        const int n = tile * 16 + s * 4 + q;
        j0[s] = row_start[n];
        j1[s] = row_start[n + 1];
    }
    // Prefetch first 16 neighbor idx per node (srcs padded; guarded).
    int idx16[4];
#pragma unroll
    for (int s = 0; s < 4; s++) {
        const int tA = j0[s] + p;
        const int v  = srcs[tA];
        idx16[s] = (tA < j1[s]) ? v : 0;
    }

    half8 buf0[8], buf1[8];

    auto issueE = [&](int s, int jc, half8* B) {
        const int off = jc - j0[s];
        int myidx;
        if (off < 16) {
            myidx = idx16[s];
        } else {
            const int tB = jc + (p & 7);
            const int v  = srcs[tB];  // padded, safe
            myidx = (tB < j1[s]) ? v : 0;
        }
        const int lsh = lbase + ((off == 8) ? 8 : 0);
#pragma unroll
        for (int i = 0; i < 8; i++) {
            const int sidx = __shfl(myidx, lsh + i);
            B[i] = *(const half8*)&xin[(size_t)sidx * 128 + c];
        }
    };
    auto adv = [&](int& s, int& jc) {
        jc += 8;
        if (jc >= j1[s]) {
            s++;
            while (s < 4 && j0[s] >= j1[s]) s++;
            jc = (s < 4) ? j0[s] : 0;
        }
    };

    // Prime
    int s_cur = 0;
    while (s_cur < 4 && j0[s_cur] >= j1[s_cur]) s_cur++;
    int jc_cur = (s_cur < 4) ? j0[s_cur] : 0;
    if (s_cur < 4) issueE(s_cur, jc_cur, buf0);

    float facc[8];
    int par = 0;
    while (s_cur < 4) {
        int s_nxt = s_cur, jc_nxt = jc_cur;
        adv(s_nxt, jc_nxt);
        if (s_nxt < 4) issueE(s_nxt, jc_nxt, par ? buf0 : buf1);

        half8* B = par ? buf1 : buf0;
        if (jc_cur == j0[s_cur]) {
#pragma unroll
            for (int u = 0; u < 8; u++) facc[u] = 0.f;
        }
        const int rem = j1[s_cur] - jc_cur;
#pragma unroll
        for (int i = 0; i < 8; i++) {
            if (i < rem) {
#pragma unroll
                for (int u = 0; u < 8; u++) facc[u] += (float)B[i][u];
            }
        }
        if (rem <= 8) {  // last epoch of this node -> finalize
            const int cnt = j1[s_cur] - j0[s_cur];
            const float inv = 1.0f / (float)(cnt > 1 ? cnt : 1);
            half8 hv;
#pragma unroll
            for (int u = 0; u < 8; u++) hv[u] = (_Float16)(facc[u] * inv);
            *(half8*)&stg[(s_cur * 4 + q) * 136 + c] = hv;
        }
        s_cur = s_nxt; jc_cur = jc_nxt; par ^= 1;
    }
    // Degree-0 nodes (vanishingly rare): zero rows
#pragma unroll
    for (int s = 0; s < 4; s++)
        if (j0[s] >= j1[s]) {
            half8 zv;
#pragma unroll
            for (int u = 0; u < 8; u++) zv[u] = (_Float16)0.f;
            *(half8*)&stg[(s * 4 + q) * 136 + c] = zv;
        }

    // Root rows, frag-direct (consecutive rows -> fully coalesced)
    half8 rt[4];
#pragma unroll
    for (int kt = 0; kt < 4; kt++)
        rt[kt] = *(const half8*)&xin[(size_t)(tile * 16 + p) * 128 + kt * 32 + q * 8];

    // A-frags for mean half (same-wave DS in-order)
    half8 am[4];
#pragma unroll
    for (int kt = 0; kt < 4; kt++)
        am[kt] = *(const half8*)&stg[p * 136 + kt * 32 + q * 8];

    // MFMA: D[16][128] = A[16][256] @ CW[128][256]^T (hi+lo)
    float4v acc[8];
#pragma unroll
    for (int nt = 0; nt < 8; nt++) {
        const float b = bias[nt * 16 + p];
        acc[nt][0] = b; acc[nt][1] = b; acc[nt][2] = b; acc[nt][3] = b;
    }
#pragma unroll
    for (int kt = 0; kt < 8; kt++) {
        const half8 a = (kt < 4) ? am[kt] : rt[kt - 4];
#pragma unroll
        for (int nt = 0; nt < 8; nt++) {
            const int widx = (nt * 16 + p) * 256 + kt * 32 + q * 8;
            const half8 bh = *(const half8*)&Wh[widx];
            const half8 be = *(const half8*)&We[widx];
            acc[nt] = __builtin_amdgcn_mfma_f32_16x16x32_f16(a, bh, acc[nt], 0, 0, 0);
            acc[nt] = __builtin_amdgcn_mfma_f32_16x16x32_f16(a, be, acc[nt], 0, 0, 0);
        }
    }

    // Epilogue: C-layout -> LDS slice -> coalesced row-major store
#pragma unroll
    for (int nt = 0; nt < 8; nt++)
#pragma unroll
        for (int r = 0; r < 4; r++) {
            float v = acc[nt][r];
            if (RELU) v = fmaxf(v, 0.f);
            stg[(q * 4 + r) * 136 + nt * 16 + p] = (_Float16)v;
        }
    {
        const int row = l >> 2;
        const int c2  = (l & 3) * 8;
#pragma unroll
        for (int i = 0; i < 4; i++)
            *(half8*)&out[(size_t)(tile * 16 + row) * 128 + i * 32 + c2] =
                *(const half8*)&stg[row * 136 + i * 32 + c2];
    }
}

// ---------------------------------------------------------------------------
// Wave-autonomous fused decoder, 16 pairs/tile, 2 tiles/wave pipelined:
// rows(A) -> prod(A) -> issue rows(B) -> MFMA(A) -> prod(B) -> MFMA(B).
// Tile B's gather latency hides under tile A's compute. No __syncthreads.
// LDS: 4 waves x [16][136] fp16 = 17408 B (slice reused A->B, same-wave order).
// ---------------------------------------------------------------------------
__global__ __launch_bounds__(256, 3) void decoder_mfma(
    const _Float16* __restrict__ z,
    const int* __restrict__ pairs,
    const _Float16* __restrict__ M1h, const float* __restrict__ bm1,
    const _Float16* __restrict__ M2h, const float* __restrict__ bm2,
    const float* __restrict__ Wm3, const float* __restrict__ bm3,
    float* __restrict__ outv)
{
    __shared__ __align__(16) _Float16 buf_all[4 * 16 * 136];
    const int wInB = threadIdx.x >> 6;
    _Float16* buf  = &buf_all[wInB * (16 * 136)];
    const int l = threadIdx.x & 63;
    const int p = l & 15;
    const int q = l >> 4;
    const int wid = blockIdx.x * 4 + wInB;
    const int tA = wid * 2;
    if (tA >= DT3) return;
    const int tB = tA + 1;
    const int c = p * 8;

    // Hoisted constants
    const float b3 = bm3[0];
    float wm3v[4], bm1v[8], bm2v[4];
#pragma unroll
    for (int nt = 0; nt < 4; nt++) wm3v[nt] = Wm3[nt * 16 + p];
#pragma unroll
    for (int nt = 0; nt < 8; nt++) bm1v[nt] = bm1[nt * 16 + p];
#pragma unroll
    for (int nt = 0; nt < 4; nt++) bm2v[nt] = bm2[nt * 16 + p];

    // Indices for both tiles
    int2 abA[4], abB[4];
#pragma unroll
    for (int it = 0; it < 4; it++) {
        abA[it] = *(const int2*)&pairs[(size_t)(tA * 16 + it * 4 + q) * 2];
        abB[it] = *(const int2*)&pairs[(size_t)(tB * 16 + it * 4 + q) * 2];
    }

    // Rows for tile A
    half8 za[4], zb[4];
#pragma unroll
    for (int it = 0; it < 4; it++) {
        za[it] = *(const half8*)&z[(size_t)abA[it].x * 128 + c];
        zb[it] = *(const half8*)&z[(size_t)abA[it].y * 128 + c];
    }

    half8 zaB[4], zbB[4];

#pragma unroll
    for (int pass = 0; pass < 2; pass++) {
        const int t = (pass == 0) ? tA : tB;

        // Products -> LDS slice (rows it*4+q)
#pragma unroll
        for (int it = 0; it < 4; it++) {
            const half8 pa = (pass == 0) ? za[it] : zaB[it];
            const half8 pb = (pass == 0) ? zb[it] : zbB[it];
            *(half8*)&buf[(it * 4 + q) * 136 + c] = pa * pb;
        }

        // A-frags (same-wave DS in-order)
        half8 a1[4];
#pragma unroll
        for (int kt = 0; kt < 4; kt++)
            a1[kt] = *(const half8*)&buf[p * 136 + kt * 32 + q * 8];

        // On pass 0: issue tile B's rows now -- they fly under the MFMA stack
        if (pass == 0) {
#pragma unroll
            for (int it = 0; it < 4; it++) {
                zaB[it] = *(const half8*)&z[(size_t)abB[it].x * 128 + c];
                zbB[it] = *(const half8*)&z[(size_t)abB[it].y * 128 + c];
            }
        }

        // L1: y1 = relu(hp @ M1^T + bm1), M=16, N=128, K=128
        float4v acc1[8];
#pragma unroll
        for (int nt = 0; nt < 8; nt++) {
            const float b = bm1v[nt];
            acc1[nt][0] = b; acc1[nt][1] = b; acc1[nt][2] = b; acc1[nt][3] = b;
        }
#pragma unroll
        for (int kt = 0; kt < 4; kt++)
#pragma unroll
            for (int nt = 0; nt < 8; nt++) {
                const half8 bh = *(const half8*)&M1h[(nt * 16 + p) * 128 + kt * 32 + q * 8];
                acc1[nt] = __builtin_amdgcn_mfma_f32_16x16x32_f16(a1[kt], bh, acc1[nt], 0, 0, 0);
            }

        // y1 -> LDS
#pragma unroll
        for (int nt = 0; nt < 8; nt++)
#pragma unroll
            for (int r = 0; r < 4; r++)
                buf[(q * 4 + r) * 136 + nt * 16 + p] = (_Float16)fmaxf(acc1[nt][r], 0.f);

        // L2: y2 = relu(y1 @ M2^T + bm2), N=64, K=128
        half8 a2[4];
#pragma unroll
        for (int kt = 0; kt < 4; kt++)
            a2[kt] = *(const half8*)&buf[p * 136 + kt * 32 + q * 8];

        float4v acc2[4];
#pragma unroll
        for (int nt = 0; nt < 4; nt++) {
            const float b = bm2v[nt];
            acc2[nt][0] = b; acc2[nt][1] = b; acc2[nt][2] = b; acc2[nt][3] = b;
        }
#pragma unroll
        for (int kt = 0; kt < 4; kt++)
#pragma unroll
            for (int nt = 0; nt < 4; nt++) {
                const half8 bh = *(const half8*)&M2h[(nt * 16 + p) * 128 + kt * 32 + q * 8];
                acc2[nt] = __builtin_amdgcn_mfma_f32_16x16x32_f16(a2[kt], bh, acc2[nt], 0, 0, 0);
            }

        // L3: out = relu(y2) . Wm3 + bm3 (reduce across 16 lanes of group)
        float part[4];
#pragma unroll
        for (int r = 0; r < 4; r++) part[r] = 0.f;
#pragma unroll
        for (int nt = 0; nt < 4; nt++)
#pragma unroll
            for (int r = 0; r < 4; r++)
                part[r] += fmaxf(acc2[nt][r], 0.f) * wm3v[nt];
#pragma unroll
        for (int s = 1; s <= 8; s <<= 1)
#pragma unroll
            for (int r = 0; r < 4; r++) part[r] += __shfl_xor(part[r], s);
        if (p == 0) {
            float4 o = make_float4(part[0] + b3, part[1] + b3, part[2] + b3, part[3] + b3);
            *(float4*)&outv[t * 16 + q * 4] = o;
        }
    }
}

// ---------------------------------------------------------------------------
extern "C" void kernel_launch(void* const* d_in, const int* in_sizes, int n_in,
                              void* d_out, int out_size, void* d_ws, size_t ws_size,
                              hipStream_t stream) {
    const float* x   = (const float*)d_in[0];
    const int*   src = (const int*)d_in[1];
    const int*   dst = src + kE;
    const int*   ep  = (const int*)d_in[2];
    const float* W1l = (const float*)d_in[3];
    const float* b1l = (const float*)d_in[4];
    const float* W1r = (const float*)d_in[5];
    const float* W2l = (const float*)d_in[6];
    const float* b2l = (const float*)d_in[7];
    const float* W2r = (const float*)d_in[8];
    const float* Wm1 = (const float*)d_in[9];
    const float* bm1 = (const float*)d_in[10];
    const float* Wm2 = (const float*)d_in[11];
    const float* bm2 = (const float*)d_in[12];
    const float* Wm3 = (const float*)d_in[13];
    const float* bm3 = (const float*)d_in[14];
    float* outv = (float*)d_out;

    char* ws = (char*)d_ws;
    size_t off = 0;
    auto alloc = [&](size_t bytes) -> void* {
        void* p = ws + off;
        off += bytes;
        off = (off + 255) & ~(size_t)255;
        return p;
    };
    int*      deg       = (int*)alloc((size_t)kN * 4);
    int*      row_start = (int*)alloc((size_t)(kN + 1) * 4);
    int*      slot      = (int*)alloc((size_t)kE * 4);
    int*      bsum      = (int*)alloc(512 * 4);
    int*      boff      = (int*)alloc(512 * 4);
    int*      srcs      = (int*)alloc((size_t)(kE + 64) * 4);  // padded
    _Float16* xh        = (_Float16*)alloc((size_t)kN * 128 * 2);
    _Float16* hh        = (_Float16*)alloc((size_t)kN * 128 * 2);
    _Float16* zh        = (_Float16*)alloc((size_t)kN * 128 * 2);
    _Float16* CW1h      = (_Float16*)alloc(128 * 256 * 2);
    _Float16* CW1e      = (_Float16*)alloc(128 * 256 * 2);
    _Float16* CW2h      = (_Float16*)alloc(128 * 256 * 2);
    _Float16* CW2e      = (_Float16*)alloc(128 * 256 * 2);
    _Float16* M1h       = (_Float16*)alloc(128 * 128 * 2);
    _Float16* M2h       = (_Float16*)alloc(64 * 128 * 2);

    // CSR build (slot-record: atomic-free second pass)
    hipMemsetAsync(deg, 0, (size_t)kN * sizeof(int), stream);
    deg_slot_kernel<<<(kE + 255) / 256, 256, 0, stream>>>(dst, deg, slot);
    scan_block_sums<<<NBS, 256, 0, stream>>>(deg, bsum);
    scan_bsums<<<1, 512, 0, stream>>>(bsum, boff);
    scan_write<<<NBS, 256, 0, stream>>>(deg, boff, row_start);
    fill2_kernel<<<(kE + 255) / 256, 256, 0, stream>>>(src, dst, row_start, slot, srcs);

    // Prep: fp16 conversions
    cvt_x_kernel<<<(kN * 128 / 8 + 255) / 256, 256, 0, stream>>>(x, xh);
    cvt_w_kernel<<<352, 256, 0, stream>>>(W1l, W1r, W2l, W2r, Wm1, Wm2,
                                          CW1h, CW1e, CW2h, CW2e, M1h, M2h);

    // Two SAGEConv layers (16 nodes/wave, ping-pong gather pipeline)
    const int convBlocks = (CT3 + 3) / 4;  // 1563
    conv_mfma<true><<<convBlocks, 256, 0, stream>>>(xh, row_start, srcs, CW1h, CW1e, b1l, hh);
    conv_mfma<false><<<convBlocks, 256, 0, stream>>>(hh, row_start, srcs, CW2h, CW2e, b2l, zh);

    // Fused decoder (16 pairs/tile, 2 tiles/wave pipelined)
    const int decBlocks = (DT3 / 2 + 3) / 4;  // 3907
    decoder_mfma<<<decBlocks, 256, 0, stream>>>(
        zh, ep, M1h, bm1, M2h, bm2, Wm3, bm3, outv);
}

// Round 9
// 696.275 us; speedup vs baseline: 1.1911x; 1.1911x over previous
//
#include <hip/hip_runtime.h>
#include <stdint.h>

typedef _Float16 half8 __attribute__((ext_vector_type(8)));
typedef float float4v __attribute__((ext_vector_type(4)));

// Problem constants
constexpr int kN = 100000;   // nodes
constexpr int kE = 1600000;  // edges
constexpr int kP = 500000;   // pairs
constexpr int NBS = (kN + 255) / 256;  // scan blocks = 391
constexpr int CT3 = kN / 16;           // 6250 conv wave-tiles (16 nodes, exact)
constexpr int DT2 = kP / 32;           // 15625 decoder wave-tiles (32 pairs, exact)

// ---------------------------------------------------------------------------
// CSR build: pass1 = histogram + slot record, scan, pass2 = atomic-free fill
// ---------------------------------------------------------------------------
__global__ void deg_slot_kernel(const int* __restrict__ dst,
                                int* __restrict__ deg, int* __restrict__ slot) {
    int e = blockIdx.x * blockDim.x + threadIdx.x;
    if (e < kE) slot[e] = atomicAdd(&deg[dst[e]], 1);
}

__global__ void scan_block_sums(const int* __restrict__ deg, int* __restrict__ bsum) {
    __shared__ int red[256];
    int t = threadIdx.x;
    int i = blockIdx.x * 256 + t;
    red[t] = (i < kN) ? deg[i] : 0;
    __syncthreads();
    for (int s = 128; s > 0; s >>= 1) {
        if (t < s) red[t] += red[t + s];
        __syncthreads();
    }
    if (t == 0) bsum[blockIdx.x] = red[0];
}

__global__ void scan_bsums(const int* __restrict__ bsum, int* __restrict__ boff) {
    __shared__ int sm[512];
    int t = threadIdx.x;
    int orig = (t < NBS) ? bsum[t] : 0;
    sm[t] = orig;
    __syncthreads();
    for (int d = 1; d < 512; d <<= 1) {
        int u = (t >= d) ? sm[t - d] : 0;
        __syncthreads();
        sm[t] += u;
        __syncthreads();
    }
    if (t < NBS) boff[t] = sm[t] - orig;  // exclusive
}

__global__ void scan_write(const int* __restrict__ deg, const int* __restrict__ boff,
                           int* __restrict__ row_start) {
    __shared__ int sm[256];
    int t = threadIdx.x;
    int i = blockIdx.x * 256 + t;
    int v = (i < kN) ? deg[i] : 0;
    sm[t] = v;
    __syncthreads();
    for (int d = 1; d < 256; d <<= 1) {
        int u = (t >= d) ? sm[t - d] : 0;
        __syncthreads();
        sm[t] += u;
        __syncthreads();
    }
    int excl = sm[t] - v + boff[blockIdx.x];
    if (i < kN) row_start[i] = excl;
    if (i == kN - 1) row_start[kN] = excl + v;
}

__global__ void fill2_kernel(const int* __restrict__ src, const int* __restrict__ dst,
                             const int* __restrict__ row_start,
                             const int* __restrict__ slot, int* __restrict__ srcs) {
    int e = blockIdx.x * blockDim.x + threadIdx.x;
    if (e < kE) srcs[row_start[dst[e]] + slot[e]] = src[e];
}

// ---------------------------------------------------------------------------
// Prep: x -> fp16; weights -> fp16 hi/lo planes
// ---------------------------------------------------------------------------
__global__ void cvt_x_kernel(const float* __restrict__ x, _Float16* __restrict__ xh) {
    const int i = (blockIdx.x * 256 + threadIdx.x) * 8;
    if (i >= kN * 128) return;
    const float4 a = *(const float4*)&x[i];
    const float4 b = *(const float4*)&x[i + 4];
    half8 v;
    v[0] = (_Float16)a.x; v[1] = (_Float16)a.y; v[2] = (_Float16)a.z; v[3] = (_Float16)a.w;
    v[4] = (_Float16)b.x; v[5] = (_Float16)b.y; v[6] = (_Float16)b.z; v[7] = (_Float16)b.w;
    *(half8*)&xh[i] = v;
}

// CW1/CW2: [128 out][256 k], k<128 -> Wl, k>=128 -> Wr. M1:[128][128], M2:[64][128].
__global__ void cvt_w_kernel(
    const float* __restrict__ W1l, const float* __restrict__ W1r,
    const float* __restrict__ W2l, const float* __restrict__ W2r,
    const float* __restrict__ Wm1, const float* __restrict__ Wm2,
    _Float16* __restrict__ CW1h, _Float16* __restrict__ CW1e,
    _Float16* __restrict__ CW2h, _Float16* __restrict__ CW2e,
    _Float16* __restrict__ M1h,  _Float16* __restrict__ M2h)
{
    const int i = blockIdx.x * 256 + threadIdx.x;
    if (i < 32768) {
        const int o = i >> 8, k = i & 255;
        const float w = (k < 128) ? W1l[o * 128 + k] : W1r[o * 128 + k - 128];
        const _Float16 h = (_Float16)w;
        CW1h[i] = h; CW1e[i] = (_Float16)(w - (float)h);
    } else if (i < 65536) {
        const int j = i - 32768;
        const int o = j >> 8, k = j & 255;
        const float w = (k < 128) ? W2l[o * 128 + k] : W2r[o * 128 + k - 128];
        const _Float16 h = (_Float16)w;
        CW2h[j] = h; CW2e[j] = (_Float16)(w - (float)h);
    } else if (i < 81920) {
        const int j = i - 65536;
        M1h[j] = (_Float16)Wm1[j];
    } else if (i < 90112) {
        const int j = i - 81920;
        M2h[j] = (_Float16)Wm2[j];
    }
}

// ---------------------------------------------------------------------------
// Single-wave fused SAGEConv, 16 nodes/block (64 threads), no __syncthreads.
// Gather: per 16-lane group, 16 neighbor idx prefetched coalesced, 16
// independent row loads batched (compiler keeps all in flight; incremental
// vmcnt consume). Concurrency from occupancy: 6250 single-wave blocks,
// target ~20 waves/CU at __launch_bounds__(64,5).
// MFMA: M=16, K=256 [mean|root], weights hi+lo from L2.
// LDS: [16][136] fp16 = 4352 B/block.
// ---------------------------------------------------------------------------
template <bool RELU>
__global__ __launch_bounds__(64, 5) void conv_mfma(
    const _Float16* __restrict__ xin,
    const int* __restrict__ row_start,
    const int* __restrict__ srcs,
    const _Float16* __restrict__ Wh,  // [128][256]
    const _Float16* __restrict__ We,  // [128][256]
    const float* __restrict__ bias,
    _Float16* __restrict__ out)
{
    __shared__ __align__(16) _Float16 stg[16 * 136];
    const int l = threadIdx.x & 63;
    const int p = l & 15;
    const int q = l >> 4;
    const int tile = blockIdx.x;
    const int c = p * 8;
    const int lbase = l & 48;

    // Group's 4 nodes: n_s = tile*16 + s*4 + q
    int j0[4], j1[4];
#pragma unroll
    for (int s = 0; s < 4; s++) {
        const int n = tile * 16 + s * 4 + q;
        j0[s] = row_start[n];
        j1[s] = row_start[n + 1];
    }
    // Prefetch first 16 neighbor idx per node (srcs padded; guarded).
    int idx16[4];
#pragma unroll
    for (int s = 0; s < 4; s++) {
        const int tA = j0[s] + p;
        const int v  = srcs[tA];
        idx16[s] = (tA < j1[s]) ? v : 0;
    }

    for (int s = 0; s < 4; s++) {
        const int cnt = j1[s] - j0[s];
        float facc[8];
#pragma unroll
        for (int u = 0; u < 8; u++) facc[u] = 0.f;

        for (int jc = j0[s]; jc < j1[s]; jc += 16) {
            int myidx;
            if (jc == j0[s]) {
                myidx = idx16[s];
            } else {
                const int tB = jc + p;
                const int v  = srcs[tB];  // padded, safe
                myidx = (tB < j1[s]) ? v : 0;
            }
            half8 rows[16];
#pragma unroll
            for (int i = 0; i < 16; i++) {
                const int sidx = __shfl(myidx, lbase + i);
                rows[i] = *(const half8*)&xin[(size_t)sidx * 128 + c];
            }
            const int rem = j1[s] - jc;
#pragma unroll
            for (int i = 0; i < 16; i++) {
                if (i < rem) {
#pragma unroll
                    for (int u = 0; u < 8; u++) facc[u] += (float)rows[i][u];
                }
            }
        }
        const float inv = 1.0f / (float)(cnt > 1 ? cnt : 1);
        half8 hv;
#pragma unroll
        for (int u = 0; u < 8; u++) hv[u] = (_Float16)(facc[u] * inv);
        *(half8*)&stg[(s * 4 + q) * 136 + c] = hv;
    }

    // Root rows, frag-direct (consecutive rows -> fully coalesced)
    half8 rt[4];
#pragma unroll
    for (int kt = 0; kt < 4; kt++)
        rt[kt] = *(const half8*)&xin[(size_t)(tile * 16 + p) * 128 + kt * 32 + q * 8];

    // A-frags for mean half (same-wave DS in-order)
    half8 am[4];
#pragma unroll
    for (int kt = 0; kt < 4; kt++)
        am[kt] = *(const half8*)&stg[p * 136 + kt * 32 + q * 8];

    // MFMA: D[16][128] = A[16][256] @ CW[128][256]^T (hi+lo)
    float4v acc[8];
#pragma unroll
    for (int nt = 0; nt < 8; nt++) {
        const float b = bias[nt * 16 + p];
        acc[nt][0] = b; acc[nt][1] = b; acc[nt][2] = b; acc[nt][3] = b;
    }
#pragma unroll
    for (int kt = 0; kt < 8; kt++) {
        const half8 a = (kt < 4) ? am[kt] : rt[kt - 4];
#pragma unroll
        for (int nt = 0; nt < 8; nt++) {
            const int widx = (nt * 16 + p) * 256 + kt * 32 + q * 8;
            const half8 bh = *(const half8*)&Wh[widx];
            const half8 be = *(const half8*)&We[widx];
            acc[nt] = __builtin_amdgcn_mfma_f32_16x16x32_f16(a, bh, acc[nt], 0, 0, 0);
            acc[nt] = __builtin_amdgcn_mfma_f32_16x16x32_f16(a, be, acc[nt], 0, 0, 0);
        }
    }

    // Epilogue: C-layout -> LDS slice -> coalesced row-major store
#pragma unroll
    for (int nt = 0; nt < 8; nt++)
#pragma unroll
        for (int r = 0; r < 4; r++) {
            float v = acc[nt][r];
            if (RELU) v = fmaxf(v, 0.f);
            stg[(q * 4 + r) * 136 + nt * 16 + p] = (_Float16)v;
        }
    {
        const int row = l >> 2;
        const int c2  = (l & 3) * 8;
#pragma unroll
        for (int i = 0; i < 4; i++)
            *(half8*)&out[(size_t)(tile * 16 + row) * 128 + i * 32 + c2] =
                *(const half8*)&stg[row * 136 + i * 32 + c2];
    }
}

// ---------------------------------------------------------------------------
// Single-wave fused decoder, 32 pairs/block (64 threads), no __syncthreads.
// R5-form body (proven no-spill). P1: batched coalesced row gathers,
// products -> LDS. L1/L2: MFMA hi-plane weights. L3: dot + reduce.
// LDS: [32][136] fp16 = 8704 B/block -> 18 blocks/CU (LDS-capped).
// ---------------------------------------------------------------------------
__global__ __launch_bounds__(64, 5) void decoder_mfma(
    const _Float16* __restrict__ z,
    const int* __restrict__ pairs,
    const _Float16* __restrict__ M1h, const float* __restrict__ bm1,
    const _Float16* __restrict__ M2h, const float* __restrict__ bm2,
    const float* __restrict__ Wm3, const float* __restrict__ bm3,
    float* __restrict__ outv)
{
    __shared__ __align__(16) _Float16 buf[32 * 136];
    const int l = threadIdx.x & 63;
    const int p = l & 15;
    const int q = l >> 4;
    const int tile = blockIdx.x;
    const int c = p * 8;

    // P1: hp = z[a]*z[b]; batch all idx loads, then all row loads (2 epochs)
    int2 ab[8];
#pragma unroll
    for (int it = 0; it < 8; it++)
        ab[it] = *(const int2*)&pairs[(size_t)(tile * 32 + it * 4 + q) * 2];
    half8 za[8], zb[8];
#pragma unroll
    for (int it = 0; it < 8; it++) {
        za[it] = *(const half8*)&z[(size_t)ab[it].x * 128 + c];
        zb[it] = *(const half8*)&z[(size_t)ab[it].y * 128 + c];
    }
#pragma unroll
    for (int it = 0; it < 8; it++)
        *(half8*)&buf[(it * 4 + q) * 136 + c] = za[it] * zb[it];

    // L1: y1 = relu(hp @ M1^T + bm1), M=32, N=128, K=128
    half8 a1[2][4];
#pragma unroll
    for (int m = 0; m < 2; m++)
#pragma unroll
        for (int kt = 0; kt < 4; kt++)
            a1[m][kt] = *(const half8*)&buf[(m * 16 + p) * 136 + kt * 32 + q * 8];

    float4v acc1[2][8];
#pragma unroll
    for (int nt = 0; nt < 8; nt++) {
        const float b = bm1[nt * 16 + p];
#pragma unroll
        for (int m = 0; m < 2; m++) {
            acc1[m][nt][0] = b; acc1[m][nt][1] = b; acc1[m][nt][2] = b; acc1[m][nt][3] = b;
        }
    }
#pragma unroll
    for (int kt = 0; kt < 4; kt++)
#pragma unroll
        for (int nt = 0; nt < 8; nt++) {
            const half8 bh = *(const half8*)&M1h[(nt * 16 + p) * 128 + kt * 32 + q * 8];
            acc1[0][nt] = __builtin_amdgcn_mfma_f32_16x16x32_f16(a1[0][kt], bh, acc1[0][nt], 0, 0, 0);
            acc1[1][nt] = __builtin_amdgcn_mfma_f32_16x16x32_f16(a1[1][kt], bh, acc1[1][nt], 0, 0, 0);
        }

    // y1 -> LDS (same-wave order: a1 reads already done)
#pragma unroll
    for (int m = 0; m < 2; m++)
#pragma unroll
        for (int nt = 0; nt < 8; nt++)
#pragma unroll
            for (int r = 0; r < 4; r++)
                buf[(m * 16 + q * 4 + r) * 136 + nt * 16 + p] =
                    (_Float16)fmaxf(acc1[m][nt][r], 0.f);

    // L2: y2 = relu(y1 @ M2^T + bm2), N=64, K=128
    half8 a2[2][4];
#pragma unroll
    for (int m = 0; m < 2; m++)
#pragma unroll
        for (int kt = 0; kt < 4; kt++)
            a2[m][kt] = *(const half8*)&buf[(m * 16 + p) * 136 + kt * 32 + q * 8];

    float4v acc2[2][4];
#pragma unroll
    for (int nt = 0; nt < 4; nt++) {
        const float b = bm2[nt * 16 + p];
#pragma unroll
        for (int m = 0; m < 2; m++) {
            acc2[m][nt][0] = b; acc2[m][nt][1] = b; acc2[m][nt][2] = b; acc2[m][nt][3] = b;
        }
    }
#pragma unroll
    for (int kt = 0; kt < 4; kt++)
#pragma unroll
        for (int nt = 0; nt < 4; nt++) {
            const half8 bh = *(const half8*)&M2h[(nt * 16 + p) * 128 + kt * 32 + q * 8];
            acc2[0][nt] = __builtin_amdgcn_mfma_f32_16x16x32_f16(a2[0][kt], bh, acc2[0][nt], 0, 0, 0);
            acc2[1][nt] = __builtin_amdgcn_mfma_f32_16x16x32_f16(a2[1][kt], bh, acc2[1][nt], 0, 0, 0);
        }

    // L3: out = relu(y2) . Wm3 + bm3
    float wm3v[4];
#pragma unroll
    for (int nt = 0; nt < 4; nt++) wm3v[nt] = Wm3[nt * 16 + p];
    const float b3 = bm3[0];
#pragma unroll
    for (int m = 0; m < 2; m++) {
        float part[4];
#pragma unroll
        for (int r = 0; r < 4; r++) part[r] = 0.f;
#pragma unroll
        for (int nt = 0; nt < 4; nt++)
#pragma unroll
            for (int r = 0; r < 4; r++)
                part[r] += fmaxf(acc2[m][nt][r], 0.f) * wm3v[nt];
#pragma unroll
        for (int s = 1; s <= 8; s <<= 1)
#pragma unroll
            for (int r = 0; r < 4; r++) part[r] += __shfl_xor(part[r], s);
        if (p == 0) {
            float4 o = make_float4(part[0] + b3, part[1] + b3, part[2] + b3, part[3] + b3);
            *(float4*)&outv[tile * 32 + m * 16 + q * 4] = o;
        }
    }
}

// ---------------------------------------------------------------------------
extern "C" void kernel_launch(void* const* d_in, const int* in_sizes, int n_in,
                              void* d_out, int out_size, void* d_ws, size_t ws_size,
                              hipStream_t stream) {
    const float* x   = (const float*)d_in[0];
    const int*   src = (const int*)d_in[1];
    const int*   dst = src + kE;
    const int*   ep  = (const int*)d_in[2];
    const float* W1l = (const float*)d_in[3];
    const float* b1l = (const float*)d_in[4];
    const float* W1r = (const float*)d_in[5];
    const float* W2l = (const float*)d_in[6];
    const float* b2l = (const float*)d_in[7];
    const float* W2r = (const float*)d_in[8];
    const float* Wm1 = (const float*)d_in[9];
    const float* bm1 = (const float*)d_in[10];
    const float* Wm2 = (const float*)d_in[11];
    const float* bm2 = (const float*)d_in[12];
    const float* Wm3 = (const float*)d_in[13];
    const float* bm3 = (const float*)d_in[14];
    float* outv = (float*)d_out;

    char* ws = (char*)d_ws;
    size_t off = 0;
    auto alloc = [&](size_t bytes) -> void* {
        void* p = ws + off;
        off += bytes;
        off = (off + 255) & ~(size_t)255;
        return p;
    };
    int*      deg       = (int*)alloc((size_t)kN * 4);
    int*      row_start = (int*)alloc((size_t)(kN + 1) * 4);
    int*      slot      = (int*)alloc((size_t)kE * 4);
    int*      bsum      = (int*)alloc(512 * 4);
    int*      boff      = (int*)alloc(512 * 4);
    int*      srcs      = (int*)alloc((size_t)(kE + 64) * 4);  // padded
    _Float16* xh        = (_Float16*)alloc((size_t)kN * 128 * 2);
    _Float16* hh        = (_Float16*)alloc((size_t)kN * 128 * 2);
    _Float16* zh        = (_Float16*)alloc((size_t)kN * 128 * 2);
    _Float16* CW1h      = (_Float16*)alloc(128 * 256 * 2);
    _Float16* CW1e      = (_Float16*)alloc(128 * 256 * 2);
    _Float16* CW2h      = (_Float16*)alloc(128 * 256 * 2);
    _Float16* CW2e      = (_Float16*)alloc(128 * 256 * 2);
    _Float16* M1h       = (_Float16*)alloc(128 * 128 * 2);
    _Float16* M2h       = (_Float16*)alloc(64 * 128 * 2);

    // CSR build (slot-record: atomic-free second pass)
    hipMemsetAsync(deg, 0, (size_t)kN * sizeof(int), stream);
    deg_slot_kernel<<<(kE + 255) / 256, 256, 0, stream>>>(dst, deg, slot);
    scan_block_sums<<<NBS, 256, 0, stream>>>(deg, bsum);
    scan_bsums<<<1, 512, 0, stream>>>(bsum, boff);
    scan_write<<<NBS, 256, 0, stream>>>(deg, boff, row_start);
    fill2_kernel<<<(kE + 255) / 256, 256, 0, stream>>>(src, dst, row_start, slot, srcs);

    // Prep: fp16 conversions
    cvt_x_kernel<<<(kN * 128 / 8 + 255) / 256, 256, 0, stream>>>(x, xh);
    cvt_w_kernel<<<352, 256, 0, stream>>>(W1l, W1r, W2l, W2r, Wm1, Wm2,
                                          CW1h, CW1e, CW2h, CW2e, M1h, M2h);

    // Two SAGEConv layers (single-wave blocks, occupancy-driven gather)
    conv_mfma<true><<<CT3, 64, 0, stream>>>(xh, row_start, srcs, CW1h, CW1e, b1l, hh);
    conv_mfma<false><<<CT3, 64, 0, stream>>>(hh, row_start, srcs, CW2h, CW2e, b2l, zh);

    // Fused decoder (single-wave blocks, R5-form)
    decoder_mfma<<<DT2, 64, 0, stream>>>(
        zh, ep, M1h, bm1, M2h, bm2, Wm3, bm3, outv);
}

// Round 10
// 608.021 us; speedup vs baseline: 1.3640x; 1.1451x over previous
//
#include <hip/hip_runtime.h>
#include <stdint.h>

typedef _Float16 half8 __attribute__((ext_vector_type(8)));
typedef float float4v __attribute__((ext_vector_type(4)));

// Problem constants
constexpr int kN = 100000;   // nodes
constexpr int kE = 1600000;  // edges
constexpr int kP = 500000;   // pairs
constexpr int NBS = (kN + 255) / 256;  // scan blocks = 391
constexpr int CT3 = kN / 16;           // 6250 conv wave-tiles (16 nodes, exact)
constexpr int DT2 = kP / 32;           // 15625 decoder wave-tiles (32 pairs, exact)

// ---------------------------------------------------------------------------
// CSR build: pass1 = histogram + slot record, scan, pass2 = atomic-free fill
// ---------------------------------------------------------------------------
__global__ void deg_slot_kernel(const int* __restrict__ dst,
                                int* __restrict__ deg, int* __restrict__ slot) {
    int e = blockIdx.x * blockDim.x + threadIdx.x;
    if (e < kE) slot[e] = atomicAdd(&deg[dst[e]], 1);
}

__global__ void scan_block_sums(const int* __restrict__ deg, int* __restrict__ bsum) {
    __shared__ int red[256];
    int t = threadIdx.x;
    int i = blockIdx.x * 256 + t;
    red[t] = (i < kN) ? deg[i] : 0;
    __syncthreads();
    for (int s = 128; s > 0; s >>= 1) {
        if (t < s) red[t] += red[t + s];
        __syncthreads();
    }
    if (t == 0) bsum[blockIdx.x] = red[0];
}

__global__ void scan_bsums(const int* __restrict__ bsum, int* __restrict__ boff) {
    __shared__ int sm[512];
    int t = threadIdx.x;
    int orig = (t < NBS) ? bsum[t] : 0;
    sm[t] = orig;
    __syncthreads();
    for (int d = 1; d < 512; d <<= 1) {
        int u = (t >= d) ? sm[t - d] : 0;
        __syncthreads();
        sm[t] += u;
        __syncthreads();
    }
    if (t < NBS) boff[t] = sm[t] - orig;  // exclusive
}

__global__ void scan_write(const int* __restrict__ deg, const int* __restrict__ boff,
                           int* __restrict__ row_start) {
    __shared__ int sm[256];
    int t = threadIdx.x;
    int i = blockIdx.x * 256 + t;
    int v = (i < kN) ? deg[i] : 0;
    sm[t] = v;
    __syncthreads();
    for (int d = 1; d < 256; d <<= 1) {
        int u = (t >= d) ? sm[t - d] : 0;
        __syncthreads();
        sm[t] += u;
        __syncthreads();
    }
    int excl = sm[t] - v + boff[blockIdx.x];
    if (i < kN) row_start[i] = excl;
    if (i == kN - 1) row_start[kN] = excl + v;
}

__global__ void fill2_kernel(const int* __restrict__ src, const int* __restrict__ dst,
                             const int* __restrict__ row_start,
                             const int* __restrict__ slot, int* __restrict__ srcs) {
    int e = blockIdx.x * blockDim.x + threadIdx.x;
    if (e < kE) srcs[row_start[dst[e]] + slot[e]] = src[e];
}

// ---------------------------------------------------------------------------
// Prep: x -> fp16; weights -> fp16 hi/lo planes
// ---------------------------------------------------------------------------
__global__ void cvt_x_kernel(const float* __restrict__ x, _Float16* __restrict__ xh) {
    const int i = (blockIdx.x * 256 + threadIdx.x) * 8;
    if (i >= kN * 128) return;
    const float4 a = *(const float4*)&x[i];
    const float4 b = *(const float4*)&x[i + 4];
    half8 v;
    v[0] = (_Float16)a.x; v[1] = (_Float16)a.y; v[2] = (_Float16)a.z; v[3] = (_Float16)a.w;
    v[4] = (_Float16)b.x; v[5] = (_Float16)b.y; v[6] = (_Float16)b.z; v[7] = (_Float16)b.w;
    *(half8*)&xh[i] = v;
}

// CW1/CW2: [128 out][256 k], k<128 -> Wl, k>=128 -> Wr. M1:[128][128], M2:[64][128].
__global__ void cvt_w_kernel(
    const float* __restrict__ W1l, const float* __restrict__ W1r,
    const float* __restrict__ W2l, const float* __restrict__ W2r,
    const float* __restrict__ Wm1, const float* __restrict__ Wm2,
    _Float16* __restrict__ CW1h, _Float16* __restrict__ CW1e,
    _Float16* __restrict__ CW2h, _Float16* __restrict__ CW2e,
    _Float16* __restrict__ M1h,  _Float16* __restrict__ M2h)
{
    const int i = blockIdx.x * 256 + threadIdx.x;
    if (i < 32768) {
        const int o = i >> 8, k = i & 255;
        const float w = (k < 128) ? W1l[o * 128 + k] : W1r[o * 128 + k - 128];
        const _Float16 h = (_Float16)w;
        CW1h[i] = h; CW1e[i] = (_Float16)(w - (float)h);
    } else if (i < 65536) {
        const int j = i - 32768;
        const int o = j >> 8, k = j & 255;
        const float w = (k < 128) ? W2l[o * 128 + k] : W2r[o * 128 + k - 128];
        const _Float16 h = (_Float16)w;
        CW2h[j] = h; CW2e[j] = (_Float16)(w - (float)h);
    } else if (i < 81920) {
        const int j = i - 65536;
        M1h[j] = (_Float16)Wm1[j];
    } else if (i < 90112) {
        const int j = i - 81920;
        M2h[j] = (_Float16)Wm2[j];
    }
}

// ---------------------------------------------------------------------------
// Single-wave fused SAGEConv, 16 nodes/block (64 threads), no __syncthreads.
// Gather: per 16-lane group, 16 neighbor idx prefetched coalesced, 16
// independent row loads batched IN REGISTERS (64 VGPR buffer -> requires the
// (64,4) launch bound: 512/4 = 128-reg cap; (64,5)'s 102-reg cap spilled it
// to scratch in R9 -- WRITE_SIZE 97 MB, +56 us/dispatch).
// Concurrency from occupancy: 6250 single-wave blocks, 16 waves/CU.
// MFMA: M=16, K=256 [mean|root], weights hi+lo from L2.
// LDS: [16][136] fp16 = 4352 B/block.
// ---------------------------------------------------------------------------
template <bool RELU>
__global__ __launch_bounds__(64, 4) void conv_mfma(
    const _Float16* __restrict__ xin,
    const int* __restrict__ row_start,
    const int* __restrict__ srcs,
    const _Float16* __restrict__ Wh,  // [128][256]
    const _Float16* __restrict__ We,  // [128][256]
    const float* __restrict__ bias,
    _Float16* __restrict__ out)
{
    __shared__ __align__(16) _Float16 stg[16 * 136];
    const int l = threadIdx.x & 63;
    const int p = l & 15;
    const int q = l >> 4;
    const int tile = blockIdx.x;
    const int c = p * 8;
    const int lbase = l & 48;

    // Group's 4 nodes: n_s = tile*16 + s*4 + q
    int j0[4], j1[4];
#pragma unroll
    for (int s = 0; s < 4; s++) {
        const int n = tile * 16 + s * 4 + q;
        j0[s] = row_start[n];
        j1[s] = row_start[n + 1];
    }
    // Prefetch first 16 neighbor idx per node (srcs padded; guarded).
    int idx16[4];
#pragma unroll
    for (int s = 0; s < 4; s++) {
        const int tA = j0[s] + p;
        const int v  = srcs[tA];
        idx16[s] = (tA < j1[s]) ? v : 0;
    }

    for (int s = 0; s < 4; s++) {
        const int cnt = j1[s] - j0[s];
        float facc[8];
#pragma unroll
        for (int u = 0; u < 8; u++) facc[u] = 0.f;

        for (int jc = j0[s]; jc < j1[s]; jc += 16) {
            int myidx;
            if (jc == j0[s]) {
                myidx = idx16[s];
            } else {
                const int tB = jc + p;
                const int v  = srcs[tB];  // padded, safe
                myidx = (tB < j1[s]) ? v : 0;
            }
            half8 rows[16];
#pragma unroll
            for (int i = 0; i < 16; i++) {
                const int sidx = __shfl(myidx, lbase + i);
                rows[i] = *(const half8*)&xin[(size_t)sidx * 128 + c];
            }
            const int rem = j1[s] - jc;
#pragma unroll
            for (int i = 0; i < 16; i++) {
                if (i < rem) {
#pragma unroll
                    for (int u = 0; u < 8; u++) facc[u] += (float)rows[i][u];
                }
            }
        }
        const float inv = 1.0f / (float)(cnt > 1 ? cnt : 1);
        half8 hv;
#pragma unroll
        for (int u = 0; u < 8; u++) hv[u] = (_Float16)(facc[u] * inv);
        *(half8*)&stg[(s * 4 + q) * 136 + c] = hv;
    }

    // Root rows, frag-direct (consecutive rows -> fully coalesced)
    half8 rt[4];
#pragma unroll
    for (int kt = 0; kt < 4; kt++)
        rt[kt] = *(const half8*)&xin[(size_t)(tile * 16 + p) * 128 + kt * 32 + q * 8];

    // A-frags for mean half (same-wave DS in-order)
    half8 am[4];
#pragma unroll
    for (int kt = 0; kt < 4; kt++)
        am[kt] = *(const half8*)&stg[p * 136 + kt * 32 + q * 8];

    // MFMA: D[16][128] = A[16][256] @ CW[128][256]^T (hi+lo)
    float4v acc[8];
#pragma unroll
    for (int nt = 0; nt < 8; nt++) {
        const float b = bias[nt * 16 + p];
        acc[nt][0] = b; acc[nt][1] = b; acc[nt][2] = b; acc[nt][3] = b;
    }
#pragma unroll
    for (int kt = 0; kt < 8; kt++) {
        const half8 a = (kt < 4) ? am[kt] : rt[kt - 4];
#pragma unroll
        for (int nt = 0; nt < 8; nt++) {
            const int widx = (nt * 16 + p) * 256 + kt * 32 + q * 8;
            const half8 bh = *(const half8*)&Wh[widx];
            const half8 be = *(const half8*)&We[widx];
            acc[nt] = __builtin_amdgcn_mfma_f32_16x16x32_f16(a, bh, acc[nt], 0, 0, 0);
            acc[nt] = __builtin_amdgcn_mfma_f32_16x16x32_f16(a, be, acc[nt], 0, 0, 0);
        }
    }

    // Epilogue: C-layout -> LDS slice -> coalesced row-major store
#pragma unroll
    for (int nt = 0; nt < 8; nt++)
#pragma unroll
        for (int r = 0; r < 4; r++) {
            float v = acc[nt][r];
            if (RELU) v = fmaxf(v, 0.f);
            stg[(q * 4 + r) * 136 + nt * 16 + p] = (_Float16)v;
        }
    {
        const int row = l >> 2;
        const int c2  = (l & 3) * 8;
#pragma unroll
        for (int i = 0; i < 4; i++)
            *(half8*)&out[(size_t)(tile * 16 + row) * 128 + i * 32 + c2] =
                *(const half8*)&stg[row * 136 + i * 32 + c2];
    }
}

// ---------------------------------------------------------------------------
// Single-wave fused decoder, 32 pairs/block (64 threads), no __syncthreads.
// R5-form body (84 VGPR, fits the (64,4) 128-reg cap). P1: batched coalesced
// row gathers, products -> LDS. L1/L2: MFMA hi-plane weights. L3: dot+reduce.
// LDS: [32][136] fp16 = 8704 B/block -> 16 blocks/CU.
// ---------------------------------------------------------------------------
__global__ __launch_bounds__(64, 4) void decoder_mfma(
    const _Float16* __restrict__ z,
    const int* __restrict__ pairs,
    const _Float16* __restrict__ M1h, const float* __restrict__ bm1,
    const _Float16* __restrict__ M2h, const float* __restrict__ bm2,
    const float* __restrict__ Wm3, const float* __restrict__ bm3,
    float* __restrict__ outv)
{
    __shared__ __align__(16) _Float16 buf[32 * 136];
    const int l = threadIdx.x & 63;
    const int p = l & 15;
    const int q = l >> 4;
    const int tile = blockIdx.x;
    const int c = p * 8;

    // P1: hp = z[a]*z[b]; batch all idx loads, then all row loads (2 epochs)
    int2 ab[8];
#pragma unroll
    for (int it = 0; it < 8; it++)
        ab[it] = *(const int2*)&pairs[(size_t)(tile * 32 + it * 4 + q) * 2];
    half8 za[8], zb[8];
#pragma unroll
    for (int it = 0; it < 8; it++) {
        za[it] = *(const half8*)&z[(size_t)ab[it].x * 128 + c];
        zb[it] = *(const half8*)&z[(size_t)ab[it].y * 128 + c];
    }
#pragma unroll
    for (int it = 0; it < 8; it++)
        *(half8*)&buf[(it * 4 + q) * 136 + c] = za[it] * zb[it];

    // L1: y1 = relu(hp @ M1^T + bm1), M=32, N=128, K=128
    half8 a1[2][4];
#pragma unroll
    for (int m = 0; m < 2; m++)
#pragma unroll
        for (int kt = 0; kt < 4; kt++)
            a1[m][kt] = *(const half8*)&buf[(m * 16 + p) * 136 + kt * 32 + q * 8];

    float4v acc1[2][8];
#pragma unroll
    for (int nt = 0; nt < 8; nt++) {
        const float b = bm1[nt * 16 + p];
#pragma unroll
        for (int m = 0; m < 2; m++) {
            acc1[m][nt][0] = b; acc1[m][nt][1] = b; acc1[m][nt][2] = b; acc1[m][nt][3] = b;
        }
    }
#pragma unroll
    for (int kt = 0; kt < 4; kt++)
#pragma unroll
        for (int nt = 0; nt < 8; nt++) {
            const half8 bh = *(const half8*)&M1h[(nt * 16 + p) * 128 + kt * 32 + q * 8];
            acc1[0][nt] = __builtin_amdgcn_mfma_f32_16x16x32_f16(a1[0][kt], bh, acc1[0][nt], 0, 0, 0);
            acc1[1][nt] = __builtin_amdgcn_mfma_f32_16x16x32_f16(a1[1][kt], bh, acc1[1][nt], 0, 0, 0);
        }

    // y1 -> LDS (same-wave order: a1 reads already done)
#pragma unroll
    for (int m = 0; m < 2; m++)
#pragma unroll
        for (int nt = 0; nt < 8; nt++)
#pragma unroll
            for (int r = 0; r < 4; r++)
                buf[(m * 16 + q * 4 + r) * 136 + nt * 16 + p] =
                    (_Float16)fmaxf(acc1[m][nt][r], 0.f);

    // L2: y2 = relu(y1 @ M2^T + bm2), N=64, K=128
    half8 a2[2][4];
#pragma unroll
    for (int m = 0; m < 2; m++)
#pragma unroll
        for (int kt = 0; kt < 4; kt++)
            a2[m][kt] = *(const half8*)&buf[(m * 16 + p) * 136 + kt * 32 + q * 8];

    float4v acc2[2][4];
#pragma unroll
    for (int nt = 0; nt < 4; nt++) {
        const float b = bm2[nt * 16 + p];
#pragma unroll
        for (int m = 0; m < 2; m++) {
            acc2[m][nt][0] = b; acc2[m][nt][1] = b; acc2[m][nt][2] = b; acc2[m][nt][3] = b;
        }
    }
#pragma unroll
    for (int kt = 0; kt < 4; kt++)
#pragma unroll
        for (int nt = 0; nt < 4; nt++) {
            const half8 bh = *(const half8*)&M2h[(nt * 16 + p) * 128 + kt * 32 + q * 8];
            acc2[0][nt] = __builtin_amdgcn_mfma_f32_16x16x32_f16(a2[0][kt], bh, acc2[0][nt], 0, 0, 0);
            acc2[1][nt] = __builtin_amdgcn_mfma_f32_16x16x32_f16(a2[1][kt], bh, acc2[1][nt], 0, 0, 0);
        }

    // L3: out = relu(y2) . Wm3 + bm3
    float wm3v[4];
#pragma unroll
    for (int nt = 0; nt < 4; nt++) wm3v[nt] = Wm3[nt * 16 + p];
    const float b3 = bm3[0];
#pragma unroll
    for (int m = 0; m < 2; m++) {
        float part[4];
#pragma unroll
        for (int r = 0; r < 4; r++) part[r] = 0.f;
#pragma unroll
        for (int nt = 0; nt < 4; nt++)
#pragma unroll
            for (int r = 0; r < 4; r++)
                part[r] += fmaxf(acc2[m][nt][r], 0.f) * wm3v[nt];
#pragma unroll
        for (int s = 1; s <= 8; s <<= 1)
#pragma unroll
            for (int r = 0; r < 4; r++) part[r] += __shfl_xor(part[r], s);
        if (p == 0) {
            float4 o = make_float4(part[0] + b3, part[1] + b3, part[2] + b3, part[3] + b3);
            *(float4*)&outv[tile * 32 + m * 16 + q * 4] = o;
        }
    }
}

// ---------------------------------------------------------------------------
extern "C" void kernel_launch(void* const* d_in, const int* in_sizes, int n_in,
                              void* d_out, int out_size, void* d_ws, size_t ws_size,
                              hipStream_t stream) {
    const float* x   = (const float*)d_in[0];
    const int*   src = (const int*)d_in[1];
    const int*   dst = src + kE;
    const int*   ep  = (const int*)d_in[2];
    const float* W1l = (const float*)d_in[3];
    const float* b1l = (const float*)d_in[4];
    const float* W1r = (const float*)d_in[5];
    const float* W2l = (const float*)d_in[6];
    const float* b2l = (const float*)d_in[7];
    const float* W2r = (const float*)d_in[8];
    const float* Wm1 = (const float*)d_in[9];
    const float* bm1 = (const float*)d_in[10];
    const float* Wm2 = (const float*)d_in[11];
    const float* bm2 = (const float*)d_in[12];
    const float* Wm3 = (const float*)d_in[13];
    const float* bm3 = (const float*)d_in[14];
    float* outv = (float*)d_out;

    char* ws = (char*)d_ws;
    size_t off = 0;
    auto alloc = [&](size_t bytes) -> void* {
        void* p = ws + off;
        off += bytes;
        off = (off + 255) & ~(size_t)255;
        return p;
    };
    int*      deg       = (int*)alloc((size_t)kN * 4);
    int*      row_start = (int*)alloc((size_t)(kN + 1) * 4);
    int*      slot      = (int*)alloc((size_t)kE * 4);
    int*      bsum      = (int*)alloc(512 * 4);
    int*      boff      = (int*)alloc(512 * 4);
    int*      srcs      = (int*)alloc((size_t)(kE + 64) * 4);  // padded
    _Float16* xh        = (_Float16*)alloc((size_t)kN * 128 * 2);
    _Float16* hh        = (_Float16*)alloc((size_t)kN * 128 * 2);
    _Float16* zh        = (_Float16*)alloc((size_t)kN * 128 * 2);
    _Float16* CW1h      = (_Float16*)alloc(128 * 256 * 2);
    _Float16* CW1e      = (_Float16*)alloc(128 * 256 * 2);
    _Float16* CW2h      = (_Float16*)alloc(128 * 256 * 2);
    _Float16* CW2e      = (_Float16*)alloc(128 * 256 * 2);
    _Float16* M1h       = (_Float16*)alloc(128 * 128 * 2);
    _Float16* M2h       = (_Float16*)alloc(64 * 128 * 2);

    // CSR build (slot-record: atomic-free second pass)
    hipMemsetAsync(deg, 0, (size_t)kN * sizeof(int), stream);
    deg_slot_kernel<<<(kE + 255) / 256, 256, 0, stream>>>(dst, deg, slot);
    scan_block_sums<<<NBS, 256, 0, stream>>>(deg, bsum);
    scan_bsums<<<1, 512, 0, stream>>>(bsum, boff);
    scan_write<<<NBS, 256, 0, stream>>>(deg, boff, row_start);
    fill2_kernel<<<(kE + 255) / 256, 256, 0, stream>>>(src, dst, row_start, slot, srcs);

    // Prep: fp16 conversions
    cvt_x_kernel<<<(kN * 128 / 8 + 255) / 256, 256, 0, stream>>>(x, xh);
    cvt_w_kernel<<<352, 256, 0, stream>>>(W1l, W1r, W2l, W2r, Wm1, Wm2,
                                          CW1h, CW1e, CW2h, CW2e, M1h, M2h);

    // Two SAGEConv layers (single-wave blocks, register-resident 16-row batch)
    conv_mfma<true><<<CT3, 64, 0, stream>>>(xh, row_start, srcs, CW1h, CW1e, b1l, hh);
    conv_mfma<false><<<CT3, 64, 0, stream>>>(hh, row_start, srcs, CW2h, CW2e, b2l, zh);

    // Fused decoder (single-wave blocks, R5-form)
    decoder_mfma<<<DT2, 64, 0, stream>>>(
        zh, ep, M1h, bm1, M2h, bm2, Wm3, bm3, outv);
}

// Round 11
// 604.724 us; speedup vs baseline: 1.3714x; 1.0055x over previous
//
#include <hip/hip_runtime.h>
#include <stdint.h>

typedef _Float16 half8 __attribute__((ext_vector_type(8)));
typedef float float4v __attribute__((ext_vector_type(4)));

// Problem constants
constexpr int kN = 100000;   // nodes
constexpr int kE = 1600000;  // edges
constexpr int kP = 500000;   // pairs
constexpr int NBS = (kN + 255) / 256;  // scan blocks = 391
constexpr int CT3 = kN / 16;           // 6250 conv wave-tiles (16 nodes, exact)
constexpr int DT2 = kP / 32;           // 15625 decoder wave-tiles (32 pairs, exact)

// ---------------------------------------------------------------------------
// Fused prep: deg+slot histogram, x->fp16, weights->fp16 planes (one dispatch)
// Blocks [0,6250): deg_slot; [6250,12500): cvt_x; [12500,12852): cvt_w.
// ---------------------------------------------------------------------------
__global__ void prep_kernel(
    const int* __restrict__ dst, int* __restrict__ deg, int* __restrict__ slot,
    const float* __restrict__ x, _Float16* __restrict__ xh,
    const float* __restrict__ W1l, const float* __restrict__ W1r,
    const float* __restrict__ W2l, const float* __restrict__ W2r,
    const float* __restrict__ Wm1, const float* __restrict__ Wm2,
    _Float16* __restrict__ CW1h, _Float16* __restrict__ CW1e,
    _Float16* __restrict__ CW2h, _Float16* __restrict__ CW2e,
    _Float16* __restrict__ M1h,  _Float16* __restrict__ M2h)
{
    const int b = blockIdx.x;
    if (b < 6250) {
        const int e = b * 256 + threadIdx.x;
        if (e < kE) slot[e] = atomicAdd(&deg[dst[e]], 1);
    } else if (b < 12500) {
        const int i = ((b - 6250) * 256 + threadIdx.x) * 8;
        if (i >= kN * 128) return;
        const float4 a = *(const float4*)&x[i];
        const float4 bb = *(const float4*)&x[i + 4];
        half8 v;
        v[0] = (_Float16)a.x;  v[1] = (_Float16)a.y;  v[2] = (_Float16)a.z;  v[3] = (_Float16)a.w;
        v[4] = (_Float16)bb.x; v[5] = (_Float16)bb.y; v[6] = (_Float16)bb.z; v[7] = (_Float16)bb.w;
        *(half8*)&xh[i] = v;
    } else {
        const int i = (b - 12500) * 256 + threadIdx.x;
        if (i < 32768) {
            const int o = i >> 8, k = i & 255;
            const float w = (k < 128) ? W1l[o * 128 + k] : W1r[o * 128 + k - 128];
            const _Float16 h = (_Float16)w;
            CW1h[i] = h; CW1e[i] = (_Float16)(w - (float)h);
        } else if (i < 65536) {
            const int j = i - 32768;
            const int o = j >> 8, k = j & 255;
            const float w = (k < 128) ? W2l[o * 128 + k] : W2r[o * 128 + k - 128];
            const _Float16 h = (_Float16)w;
            CW2h[j] = h; CW2e[j] = (_Float16)(w - (float)h);
        } else if (i < 81920) {
            const int j = i - 65536;
            M1h[j] = (_Float16)Wm1[j];
        } else if (i < 90112) {
            const int j = i - 81920;
            M2h[j] = (_Float16)Wm2[j];
        }
    }
}

// ---------------------------------------------------------------------------
// Scan + atomic-free CSR fill
// ---------------------------------------------------------------------------
__global__ void scan_block_sums(const int* __restrict__ deg, int* __restrict__ bsum) {
    __shared__ int red[256];
    int t = threadIdx.x;
    int i = blockIdx.x * 256 + t;
    red[t] = (i < kN) ? deg[i] : 0;
    __syncthreads();
    for (int s = 128; s > 0; s >>= 1) {
        if (t < s) red[t] += red[t + s];
        __syncthreads();
    }
    if (t == 0) bsum[blockIdx.x] = red[0];
}

__global__ void scan_bsums(const int* __restrict__ bsum, int* __restrict__ boff) {
    __shared__ int sm[512];
    int t = threadIdx.x;
    int orig = (t < NBS) ? bsum[t] : 0;
    sm[t] = orig;
    __syncthreads();
    for (int d = 1; d < 512; d <<= 1) {
        int u = (t >= d) ? sm[t - d] : 0;
        __syncthreads();
        sm[t] += u;
        __syncthreads();
    }
    if (t < NBS) boff[t] = sm[t] - orig;  // exclusive
}

__global__ void scan_write(const int* __restrict__ deg, const int* __restrict__ boff,
                           int* __restrict__ row_start) {
    __shared__ int sm[256];
    int t = threadIdx.x;
    int i = blockIdx.x * 256 + t;
    int v = (i < kN) ? deg[i] : 0;
    sm[t] = v;
    __syncthreads();
    for (int d = 1; d < 256; d <<= 1) {
        int u = (t >= d) ? sm[t - d] : 0;
        __syncthreads();
        sm[t] += u;
        __syncthreads();
    }
    int excl = sm[t] - v + boff[blockIdx.x];
    if (i < kN) row_start[i] = excl;
    if (i == kN - 1) row_start[kN] = excl + v;
}

__global__ void fill2_kernel(const int* __restrict__ src, const int* __restrict__ dst,
                             const int* __restrict__ row_start,
                             const int* __restrict__ slot, int* __restrict__ srcs) {
    int e = blockIdx.x * blockDim.x + threadIdx.x;
    if (e < kE) srcs[row_start[dst[e]] + slot[e]] = src[e];
}

// ---------------------------------------------------------------------------
// Single-wave fused SAGEConv, 16 nodes/block (64 threads), no __syncthreads.
// Gather: per 16-lane group, 16 idx prefetched coalesced; 16 row loads
// batched in registers with a sched_barrier(0) pinning ALL loads before the
// consume (R10's 64-VGPR allocation proved the compiler otherwise splits the
// batch to ~4 in flight). (64,4) bound = 128-reg cap; ~112 live at barrier.
// MFMA: M=16, K=256 [mean|root], weights hi+lo from L2.
// LDS: [16][136] fp16 = 4352 B/block.
// ---------------------------------------------------------------------------
template <bool RELU>
__global__ __launch_bounds__(64, 4) void conv_mfma(
    const _Float16* __restrict__ xin,
    const int* __restrict__ row_start,
    const int* __restrict__ srcs,
    const _Float16* __restrict__ Wh,  // [128][256]
    const _Float16* __restrict__ We,  // [128][256]
    const float* __restrict__ bias,
    _Float16* __restrict__ out)
{
    __shared__ __align__(16) _Float16 stg[16 * 136];
    const int l = threadIdx.x & 63;
    const int p = l & 15;
    const int q = l >> 4;
    const int tile = blockIdx.x;
    const int c = p * 8;
    const int lbase = l & 48;

    // Group's 4 nodes: n_s = tile*16 + s*4 + q
    int j0[4], j1[4];
#pragma unroll
    for (int s = 0; s < 4; s++) {
        const int n = tile * 16 + s * 4 + q;
        j0[s] = row_start[n];
        j1[s] = row_start[n + 1];
    }
    // Prefetch first 16 neighbor idx per node (srcs padded; guarded).
    int idx16[4];
#pragma unroll
    for (int s = 0; s < 4; s++) {
        const int tA = j0[s] + p;
        const int v  = srcs[tA];
        idx16[s] = (tA < j1[s]) ? v : 0;
    }

#pragma unroll
    for (int s = 0; s < 4; s++) {
        const int cnt = j1[s] - j0[s];
        float facc[8];
#pragma unroll
        for (int u = 0; u < 8; u++) facc[u] = 0.f;

        for (int jc = j0[s]; jc < j1[s]; jc += 16) {
            int myidx;
            if (jc == j0[s]) {
                myidx = idx16[s];
            } else {
                const int tB = jc + p;
                const int v  = srcs[tB];  // padded, safe
                myidx = (tB < j1[s]) ? v : 0;
            }
            half8 rows[16];
#pragma unroll
            for (int i = 0; i < 16; i++) {
                const int sidx = __shfl(myidx, lbase + i);
                rows[i] = *(const half8*)&xin[(size_t)sidx * 128 + c];
            }
            // Pin: every row load issued before any consume (16 KB/wave in flight)
            __builtin_amdgcn_sched_barrier(0);
            const int rem = j1[s] - jc;
#pragma unroll
            for (int i = 0; i < 16; i++) {
                if (i < rem) {
#pragma unroll
                    for (int u = 0; u < 8; u++) facc[u] += (float)rows[i][u];
                }
            }
        }
        const float inv = 1.0f / (float)(cnt > 1 ? cnt : 1);
        half8 hv;
#pragma unroll
        for (int u = 0; u < 8; u++) hv[u] = (_Float16)(facc[u] * inv);
        *(half8*)&stg[(s * 4 + q) * 136 + c] = hv;
    }

    // Root rows, frag-direct (consecutive rows -> fully coalesced)
    half8 rt[4];
#pragma unroll
    for (int kt = 0; kt < 4; kt++)
        rt[kt] = *(const half8*)&xin[(size_t)(tile * 16 + p) * 128 + kt * 32 + q * 8];

    // A-frags for mean half (same-wave DS in-order)
    half8 am[4];
#pragma unroll
    for (int kt = 0; kt < 4; kt++)
        am[kt] = *(const half8*)&stg[p * 136 + kt * 32 + q * 8];

    // MFMA: D[16][128] = A[16][256] @ CW[128][256]^T (hi+lo)
    float4v acc[8];
#pragma unroll
    for (int nt = 0; nt < 8; nt++) {
        const float b = bias[nt * 16 + p];
        acc[nt][0] = b; acc[nt][1] = b; acc[nt][2] = b; acc[nt][3] = b;
    }
#pragma unroll
    for (int kt = 0; kt < 8; kt++) {
        const half8 a = (kt < 4) ? am[kt] : rt[kt - 4];
#pragma unroll
        for (int nt = 0; nt < 8; nt++) {
            const int widx = (nt * 16 + p) * 256 + kt * 32 + q * 8;
            const half8 bh = *(const half8*)&Wh[widx];
            const half8 be = *(const half8*)&We[widx];
            acc[nt] = __builtin_amdgcn_mfma_f32_16x16x32_f16(a, bh, acc[nt], 0, 0, 0);
            acc[nt] = __builtin_amdgcn_mfma_f32_16x16x32_f16(a, be, acc[nt], 0, 0, 0);
        }
    }

    // Epilogue: C-layout -> LDS slice -> coalesced row-major store
#pragma unroll
    for (int nt = 0; nt < 8; nt++)
#pragma unroll
        for (int r = 0; r < 4; r++) {
            float v = acc[nt][r];
            if (RELU) v = fmaxf(v, 0.f);
            stg[(q * 4 + r) * 136 + nt * 16 + p] = (_Float16)v;
        }
    {
        const int row = l >> 2;
        const int c2  = (l & 3) * 8;
#pragma unroll
        for (int i = 0; i < 4; i++)
            *(half8*)&out[(size_t)(tile * 16 + row) * 128 + i * 32 + c2] =
                *(const half8*)&stg[row * 136 + i * 32 + c2];
    }
}

// ---------------------------------------------------------------------------
// Single-wave fused decoder, 32 pairs/block (64 threads), no __syncthreads.
// P1: batched coalesced row gathers with sched_barrier pin (16 loads in
// flight), products -> LDS. L1/L2: MFMA hi-plane weights. L3: dot+reduce.
// LDS: [32][136] fp16 = 8704 B/block.
// ---------------------------------------------------------------------------
__global__ __launch_bounds__(64, 4) void decoder_mfma(
    const _Float16* __restrict__ z,
    const int* __restrict__ pairs,
    const _Float16* __restrict__ M1h, const float* __restrict__ bm1,
    const _Float16* __restrict__ M2h, const float* __restrict__ bm2,
    const float* __restrict__ Wm3, const float* __restrict__ bm3,
    float* __restrict__ outv)
{
    __shared__ __align__(16) _Float16 buf[32 * 136];
    const int l = threadIdx.x & 63;
    const int p = l & 15;
    const int q = l >> 4;
    const int tile = blockIdx.x;
    const int c = p * 8;

    // P1: hp = z[a]*z[b]; batch all idx loads, then all row loads (2 epochs)
    int2 ab[8];
#pragma unroll
    for (int it = 0; it < 8; it++)
        ab[it] = *(const int2*)&pairs[(size_t)(tile * 32 + it * 4 + q) * 2];
    half8 za[8], zb[8];
#pragma unroll
    for (int it = 0; it < 8; it++) {
        za[it] = *(const half8*)&z[(size_t)ab[it].x * 128 + c];
        zb[it] = *(const half8*)&z[(size_t)ab[it].y * 128 + c];
    }
    __builtin_amdgcn_sched_barrier(0);
#pragma unroll
    for (int it = 0; it < 8; it++)
        *(half8*)&buf[(it * 4 + q) * 136 + c] = za[it] * zb[it];

    // L1: y1 = relu(hp @ M1^T + bm1), M=32, N=128, K=128
    half8 a1[2][4];
#pragma unroll
    for (int m = 0; m < 2; m++)
#pragma unroll
        for (int kt = 0; kt < 4; kt++)
            a1[m][kt] = *(const half8*)&buf[(m * 16 + p) * 136 + kt * 32 + q * 8];

    float4v acc1[2][8];
#pragma unroll
    for (int nt = 0; nt < 8; nt++) {
        const float b = bm1[nt * 16 + p];
#pragma unroll
        for (int m = 0; m < 2; m++) {
            acc1[m][nt][0] = b; acc1[m][nt][1] = b; acc1[m][nt][2] = b; acc1[m][nt][3] = b;
        }
    }
#pragma unroll
    for (int kt = 0; kt < 4; kt++)
#pragma unroll
        for (int nt = 0; nt < 8; nt++) {
            const half8 bh = *(const half8*)&M1h[(nt * 16 + p) * 128 + kt * 32 + q * 8];
            acc1[0][nt] = __builtin_amdgcn_mfma_f32_16x16x32_f16(a1[0][kt], bh, acc1[0][nt], 0, 0, 0);
            acc1[1][nt] = __builtin_amdgcn_mfma_f32_16x16x32_f16(a1[1][kt], bh, acc1[1][nt], 0, 0, 0);
        }

    // y1 -> LDS (same-wave order: a1 reads already done)
#pragma unroll
    for (int m = 0; m < 2; m++)
#pragma unroll
        for (int nt = 0; nt < 8; nt++)
#pragma unroll
            for (int r = 0; r < 4; r++)
                buf[(m * 16 + q * 4 + r) * 136 + nt * 16 + p] =
                    (_Float16)fmaxf(acc1[m][nt][r], 0.f);

    // L2: y2 = relu(y1 @ M2^T + bm2), N=64, K=128
    half8 a2[2][4];
#pragma unroll
    for (int m = 0; m < 2; m++)
#pragma unroll
        for (int kt = 0; kt < 4; kt++)
            a2[m][kt] = *(const half8*)&buf[(m * 16 + p) * 136 + kt * 32 + q * 8];

    float4v acc2[2][4];
#pragma unroll
    for (int nt = 0; nt < 4; nt++) {
        const float b = bm2[nt * 16 + p];
#pragma unroll
        for (int m = 0; m < 2; m++) {
            acc2[m][nt][0] = b; acc2[m][nt][1] = b; acc2[m][nt][2] = b; acc2[m][nt][3] = b;
        }
    }
#pragma unroll
    for (int kt = 0; kt < 4; kt++)
#pragma unroll
        for (int nt = 0; nt < 4; nt++) {
            const half8 bh = *(const half8*)&M2h[(nt * 16 + p) * 128 + kt * 32 + q * 8];
            acc2[0][nt] = __builtin_amdgcn_mfma_f32_16x16x32_f16(a2[0][kt], bh, acc2[0][nt], 0, 0, 0);
            acc2[1][nt] = __builtin_amdgcn_mfma_f32_16x16x32_f16(a2[1][kt], bh, acc2[1][nt], 0, 0, 0);
        }

    // L3: out = relu(y2) . Wm3 + bm3
    float wm3v[4];
#pragma unroll
    for (int nt = 0; nt < 4; nt++) wm3v[nt] = Wm3[nt * 16 + p];
    const float b3 = bm3[0];
#pragma unroll
    for (int m = 0; m < 2; m++) {
        float part[4];
#pragma unroll
        for (int r = 0; r < 4; r++) part[r] = 0.f;
#pragma unroll
        for (int nt = 0; nt < 4; nt++)
#pragma unroll
            for (int r = 0; r < 4; r++)
                part[r] += fmaxf(acc2[m][nt][r], 0.f) * wm3v[nt];
#pragma unroll
        for (int s = 1; s <= 8; s <<= 1)
#pragma unroll
            for (int r = 0; r < 4; r++) part[r] += __shfl_xor(part[r], s);
        if (p == 0) {
            float4 o = make_float4(part[0] + b3, part[1] + b3, part[2] + b3, part[3] + b3);
            *(float4*)&outv[tile * 32 + m * 16 + q * 4] = o;
        }
    }
}

// ---------------------------------------------------------------------------
extern "C" void kernel_launch(void* const* d_in, const int* in_sizes, int n_in,
                              void* d_out, int out_size, void* d_ws, size_t ws_size,
                              hipStream_t stream) {
    const float* x   = (const float*)d_in[0];
    const int*   src = (const int*)d_in[1];
    const int*   dst = src + kE;
    const int*   ep  = (const int*)d_in[2];
    const float* W1l = (const float*)d_in[3];
    const float* b1l = (const float*)d_in[4];
    const float* W1r = (const float*)d_in[5];
    const float* W2l = (const float*)d_in[6];
    const float* b2l = (const float*)d_in[7];
    const float* W2r = (const float*)d_in[8];
    const float* Wm1 = (const float*)d_in[9];
    const float* bm1 = (const float*)d_in[10];
    const float* Wm2 = (const float*)d_in[11];
    const float* bm2 = (const float*)d_in[12];
    const float* Wm3 = (const float*)d_in[13];
    const float* bm3 = (const float*)d_in[14];
    float* outv = (float*)d_out;

    char* ws = (char*)d_ws;
    size_t off = 0;
    auto alloc = [&](size_t bytes) -> void* {
        void* p = ws + off;
        off += bytes;
        off = (off + 255) & ~(size_t)255;
        return p;
    };
    int*      deg       = (int*)alloc((size_t)kN * 4);
    int*      row_start = (int*)alloc((size_t)(kN + 1) * 4);
    int*      slot      = (int*)alloc((size_t)kE * 4);
    int*      bsum      = (int*)alloc(512 * 4);
    int*      boff      = (int*)alloc(512 * 4);
    int*      srcs      = (int*)alloc((size_t)(kE + 64) * 4);  // padded
    _Float16* xh        = (_Float16*)alloc((size_t)kN * 128 * 2);
    _Float16* hh        = (_Float16*)alloc((size_t)kN * 128 * 2);
    _Float16* zh        = (_Float16*)alloc((size_t)kN * 128 * 2);
    _Float16* CW1h      = (_Float16*)alloc(128 * 256 * 2);
    _Float16* CW1e      = (_Float16*)alloc(128 * 256 * 2);
    _Float16* CW2h      = (_Float16*)alloc(128 * 256 * 2);
    _Float16* CW2e      = (_Float16*)alloc(128 * 256 * 2);
    _Float16* M1h       = (_Float16*)alloc(128 * 128 * 2);
    _Float16* M2h       = (_Float16*)alloc(64 * 128 * 2);

    // Fused prep (histogram+slot, cvt_x, cvt_w) + scan + atomic-free fill
    hipMemsetAsync(deg, 0, (size_t)kN * sizeof(int), stream);
    prep_kernel<<<12852, 256, 0, stream>>>(dst, deg, slot, x, xh,
                                           W1l, W1r, W2l, W2r, Wm1, Wm2,
                                           CW1h, CW1e, CW2h, CW2e, M1h, M2h);
    scan_block_sums<<<NBS, 256, 0, stream>>>(deg, bsum);
    scan_bsums<<<1, 512, 0, stream>>>(bsum, boff);
    scan_write<<<NBS, 256, 0, stream>>>(deg, boff, row_start);
    fill2_kernel<<<(kE + 255) / 256, 256, 0, stream>>>(src, dst, row_start, slot, srcs);

    // Two SAGEConv layers (single-wave blocks, pinned 16-row batches)
    conv_mfma<true><<<CT3, 64, 0, stream>>>(xh, row_start, srcs, CW1h, CW1e, b1l, hh);
    conv_mfma<false><<<CT3, 64, 0, stream>>>(hh, row_start, srcs, CW2h, CW2e, b2l, zh);

    // Fused decoder (single-wave blocks, pinned row batch)
    decoder_mfma<<<DT2, 64, 0, stream>>>(
        zh, ep, M1h, bm1, M2h, bm2, Wm3, bm3, outv);
}